// Round 5
// baseline (142.911 us; speedup 1.0000x reference)
//
#include <hip/hip_runtime.h>
#include <stdint.h>

#define N 2048
#define TILE 128
#define BK 32
#define KHALF 1024
#define KI (KHALF / BK)   // 32 K-iterations per K-group
#define LDSW 40           // padded LDS row stride in u16 (80 B)
#define ABUF 5120         // u16 per staging buffer (128*LDSW)
#define NN ((size_t)N * (size_t)N)

typedef unsigned short u16;
typedef __bf16 bf16x8 __attribute__((ext_vector_type(8)));
typedef unsigned short ushortx8 __attribute__((ext_vector_type(8)));
typedef float floatx4 __attribute__((ext_vector_type(4)));

static __device__ __forceinline__ u16 f2bf(float f) {
  unsigned int u = __builtin_bit_cast(unsigned int, f);
  return (u16)((u + 0x7fffu + ((u >> 16) & 1u)) >> 16);  // RNE, finite inputs
}

// ---------------------------------------------------------------------------
// cast + transpose: Ab[r][c] = bf16(A[r][c]); Abt[c][r] = bf16(A[r][c])
// ---------------------------------------------------------------------------
__global__ void cast_tr(const float* __restrict__ A, u16* __restrict__ Ab,
                        u16* __restrict__ Abt) {
  __shared__ float tile[32][33];
  const int tx = threadIdx.x, ty = threadIdx.y;
  const int c = blockIdx.x * 32 + tx;
#pragma unroll
  for (int i = 0; i < 4; i++) {
    const int r = blockIdx.y * 32 + ty + i * 8;
    const float v = A[r * N + c];
    Ab[r * N + c] = f2bf(v);
    tile[ty + i * 8][tx] = v;
  }
  __syncthreads();
  const int r2 = blockIdx.y * 32 + tx;
#pragma unroll
  for (int i = 0; i < 4; i++) {
    const int c2 = blockIdx.x * 32 + ty + i * 8;
    Abt[c2 * N + r2] = f2bf(tile[tx][ty + i * 8]);
  }
}

// ---------------------------------------------------------------------------
// Core: 512 threads = 8 waves. Waves 0-3 (group 0) accumulate k in [0,1024),
// waves 4-7 (group 1) k in [1024,2048), same 128x128 output tile. Each wave
// owns a 64x64 subtile (4x4 MFMA accs). Register prefetch distance 3 via
// plain global_load_dwordx4; double-buffered LDS per group; ONE barrier/iter
// (read buf[i&1], write buf[(i+1)&1] — last read of overwritten buffer
// finished before this iter's top barrier).
// smem carve (u16 idx): A: g*2*ABUF + buf*ABUF  (0..20479)
//                       B: 20480 + g*2*ABUF + buf*ABUF (20480..40959) = 80 KB
// ---------------------------------------------------------------------------
__device__ __forceinline__ void gemm_core(u16* smem, const u16* __restrict__ L,
                                          const u16* __restrict__ Rt,
                                          floatx4 acc[4][4]) {
  const int t = threadIdx.x;
  const int g = t >> 8;          // K-group
  const int tl = t & 255;        // thread-in-group
  const int row0 = blockIdx.y * TILE;
  const int col0 = blockIdx.x * TILE;

  // staging: thread covers row tl>>1, 32B chunk (tl&1) of each 128x32 tile
  const int srow = tl >> 1;
  const int sc = (tl & 1) * 16;  // u16 offset
  const u16* gA = L + (size_t)(row0 + srow) * N + g * KHALF + sc;
  const u16* gB = Rt + (size_t)(col0 + srow) * N + g * KHALF + sc;
  const int wbA = g * (2 * ABUF) + srow * LDSW + sc;
  const int wbB = 20480 + wbA;

  const int lane = t & 63;
  const int wg = (t >> 6) & 3;   // wave-in-group
  const int wr = (wg >> 1) * 64;
  const int wc = (wg & 1) * 64;
  const int lr = lane & 15;
  const int q = lane >> 4;
  const int raA = g * (2 * ABUF) + (wr + lr) * LDSW + q * 8;
  const int raB = 20480 + g * (2 * ABUF) + (wc + lr) * LDSW + q * 8;

#pragma unroll
  for (int i = 0; i < 4; i++)
#pragma unroll
    for (int j = 0; j < 4; j++) acc[i][j] = (floatx4){0.f, 0.f, 0.f, 0.f};

  ushortx8 rA[4][2], rB[4][2];
#pragma unroll
  for (int s = 0; s < 3; s++) {
    rA[s][0] = *(const ushortx8*)(gA + s * BK);
    rA[s][1] = *(const ushortx8*)(gA + s * BK + 8);
    rB[s][0] = *(const ushortx8*)(gB + s * BK);
    rB[s][1] = *(const ushortx8*)(gB + s * BK + 8);
  }
  *(ushortx8*)(&smem[wbA]) = rA[0][0];
  *(ushortx8*)(&smem[wbA + 8]) = rA[0][1];
  *(ushortx8*)(&smem[wbB]) = rB[0][0];
  *(ushortx8*)(&smem[wbB + 8]) = rB[0][1];

  // cur/nxt buffer indices derive from stage literal s (i&1 == s&1).
#define GSTEP(i, s)                                                           \
  {                                                                           \
    __syncthreads();                                                          \
    if ((i) + 3 < KI) {                                                       \
      rA[((s) + 3) & 3][0] = *(const ushortx8*)(gA + ((i) + 3) * BK);         \
      rA[((s) + 3) & 3][1] = *(const ushortx8*)(gA + ((i) + 3) * BK + 8);     \
      rB[((s) + 3) & 3][0] = *(const ushortx8*)(gB + ((i) + 3) * BK);         \
      rB[((s) + 3) & 3][1] = *(const ushortx8*)(gB + ((i) + 3) * BK + 8);     \
    }                                                                         \
    bf16x8 af[4], bq[4];                                                      \
    _Pragma("unroll") for (int mt = 0; mt < 4; mt++) af[mt] =                 \
        __builtin_bit_cast(bf16x8, *(const ushortx8*)&smem[                   \
            raA + ((s) & 1) * ABUF + mt * 16 * LDSW]);                        \
    _Pragma("unroll") for (int nt = 0; nt < 4; nt++) bq[nt] =                 \
        __builtin_bit_cast(bf16x8, *(const ushortx8*)&smem[                   \
            raB + ((s) & 1) * ABUF + nt * 16 * LDSW]);                        \
    _Pragma("unroll") for (int mt = 0; mt < 4; mt++)                          \
        _Pragma("unroll") for (int nt = 0; nt < 4; nt++) acc[mt][nt] =        \
            __builtin_amdgcn_mfma_f32_16x16x32_bf16(af[mt], bq[nt],           \
                                                    acc[mt][nt], 0, 0, 0);    \
    if ((i) + 1 < KI) {                                                       \
      const int nb = (((s) + 1) & 1) * ABUF;                                  \
      *(ushortx8*)(&smem[wbA + nb]) = rA[((s) + 1) & 3][0];                   \
      *(ushortx8*)(&smem[wbA + nb + 8]) = rA[((s) + 1) & 3][1];               \
      *(ushortx8*)(&smem[wbB + nb]) = rB[((s) + 1) & 3][0];                   \
      *(ushortx8*)(&smem[wbB + nb + 8]) = rB[((s) + 1) & 3][1];               \
    }                                                                         \
  }

  for (int io = 0; io < KI; io += 4) {
    GSTEP(io + 0, 0)
    GSTEP(io + 1, 1)
    GSTEP(io + 2, 2)
    GSTEP(io + 3, 3)
  }
#undef GSTEP
}

// Cross-group combine: group 1 publishes accs via LDS (aliases dead staging
// buffers); group 0 ends up holding the full-K sums.
__device__ __forceinline__ void combine(u16* smem, floatx4 acc[4][4]) {
  float* smf = (float*)smem;
  const int t = threadIdx.x;
  const int g = t >> 8;
  const int lane = t & 63;
  const int wg = (t >> 6) & 3;
  __syncthreads();  // all waves past their last LDS reads of the K-loop
  if (g == 1) {
#pragma unroll
    for (int mt = 0; mt < 4; mt++)
#pragma unroll
      for (int nt = 0; nt < 4; nt++)
        *(floatx4*)&smf[wg * 4096 + (mt * 4 + nt) * 256 + lane * 4] =
            acc[mt][nt];
  }
  __syncthreads();
  if (g == 0) {
#pragma unroll
    for (int mt = 0; mt < 4; mt++)
#pragma unroll
      for (int nt = 0; nt < 4; nt++)
        acc[mt][nt] += *(const floatx4*)&smf[wg * 4096 + (mt * 4 + nt) * 256 +
                                             lane * 4];
  }
}

// GEMM1: Mb = bf16(A@A); deg[row] += rowsum(M) (fused, LDS then global atomic)
__global__ __launch_bounds__(512, 2) void gemm1(const u16* __restrict__ Ab,
                                                const u16* __restrict__ Abt,
                                                u16* __restrict__ Mb,
                                                float* __restrict__ deg) {
  __shared__ __align__(16) u16 smem[40960];
  floatx4 acc[4][4];
  gemm_core(smem, Ab, Abt, acc);
  combine(smem, acc);

  float* rs = (float*)smem + 16384;  // disjoint from combine area
  const int t = threadIdx.x;
  const int row0 = blockIdx.y * TILE, col0 = blockIdx.x * TILE;
  if (t < TILE) rs[t] = 0.f;
  __syncthreads();
  if ((t >> 8) == 0) {
    const int lane = t & 63, wg = (t >> 6) & 3;
    const int wr = (wg >> 1) * 64, wc = (wg & 1) * 64;
    const int lr = lane & 15, q = lane >> 4;
    float trs[4][4];
#pragma unroll
    for (int mt = 0; mt < 4; mt++)
#pragma unroll
      for (int r = 0; r < 4; r++) trs[mt][r] = 0.f;
#pragma unroll
    for (int mt = 0; mt < 4; mt++)
#pragma unroll
      for (int nt = 0; nt < 4; nt++)
#pragma unroll
        for (int r = 0; r < 4; r++) {
          const float v = acc[mt][nt][r];
          const int rr = row0 + wr + mt * 16 + q * 4 + r;
          const int cc = col0 + wc + nt * 16 + lr;
          Mb[(size_t)rr * N + cc] = f2bf(v);
          trs[mt][r] += v;
        }
#pragma unroll
    for (int mt = 0; mt < 4; mt++)
#pragma unroll
      for (int r = 0; r < 4; r++)
        atomicAdd(&rs[wr + mt * 16 + q * 4 + r], trs[mt][r]);
  }
  __syncthreads();
  if (t < TILE) atomicAdd(&deg[row0 + t], rs[t]);
}

// GEMM2 + fused norm epilogue: out = (8*(M@A) + 2*A) / (4*deg+1) row-scaled
__global__ __launch_bounds__(512, 2) void gemm2(const u16* __restrict__ Mb,
                                                const u16* __restrict__ Abt,
                                                const float* __restrict__ A,
                                                const float* __restrict__ deg,
                                                float* __restrict__ out) {
  __shared__ __align__(16) u16 smem[40960];
  floatx4 acc[4][4];
  gemm_core(smem, Mb, Abt, acc);
  combine(smem, acc);

  const int t = threadIdx.x;
  if ((t >> 8) != 0) return;
  const int row0 = blockIdx.y * TILE, col0 = blockIdx.x * TILE;
  const int lane = t & 63, wg = (t >> 6) & 3;
  const int wr = (wg >> 1) * 64, wc = (wg & 1) * 64;
  const int lr = lane & 15, q = lane >> 4;
#pragma unroll
  for (int mt = 0; mt < 4; mt++)
#pragma unroll
    for (int r = 0; r < 4; r++) {
      const int rr = row0 + wr + mt * 16 + q * 4 + r;
      float d = 4.f * deg[rr] + 1.f;
      if (d <= 1e-10f) d = 1.f;
      const float rd = 1.f / d;
#pragma unroll
      for (int nt = 0; nt < 4; nt++) {
        const int cc = col0 + wc + nt * 16 + lr;
        out[(size_t)rr * N + cc] =
            (8.f * acc[mt][nt][r] + 2.f * A[(size_t)rr * N + cc]) * rd;
      }
    }
}

extern "C" void kernel_launch(void* const* d_in, const int* in_sizes, int n_in,
                              void* d_out, int out_size, void* d_ws, size_t ws_size,
                              hipStream_t stream) {
  const float* A = (const float*)d_in[0];
  // GTConv weights (d_in[1..3]) are irrelevant: softmax over a singleton axis
  // is identically 1, so each conv output is exactly 2*A.
  float* out = (float*)d_out;
  char* ws = (char*)d_ws;
  u16* Ab = (u16*)ws;                        // 8 MB bf16 A row-major
  u16* Abt = (u16*)(ws + NN * 2);            // 8 MB bf16 A transposed
  u16* Mb = (u16*)(ws + NN * 4);             // 8 MB bf16 M = A@A
  float* deg = (float*)(ws + NN * 6);        // 8 KB row sums of M

  hipMemsetAsync(deg, 0, N * sizeof(float), stream);
  cast_tr<<<dim3(N / 32, N / 32), dim3(32, 8), 0, stream>>>(A, Ab, Abt);
  gemm1<<<dim3(16, 16), 512, 0, stream>>>(Ab, Abt, Mb, deg);
  gemm2<<<dim3(16, 16), 512, 0, stream>>>(Mb, Abt, A, deg, out);
}